// Round 1
// baseline (208.180 us; speedup 1.0000x reference)
//
#include <hip/hip_runtime.h>
#include <hip/hip_bf16.h>

#define N_ 2048
#define D_ 128
#define B_ 8
#define IM 32                    // rows per gemm block
#define BK 128                   // K per step
#define NKI (N_ / BK)            // 16
#define VROWS 144                // 130 useful cols (128 emb + hsq + 1) padded
#define NBLK (B_ * (N_ / IM))    // 512

typedef __attribute__((ext_vector_type(8))) short short8;
typedef __attribute__((ext_vector_type(4))) float f32x4;
typedef __attribute__((ext_vector_type(4))) unsigned short ushort4v;

__device__ __forceinline__ unsigned short f2bf(float x) {
  unsigned int u = __builtin_bit_cast(unsigned int, x);
  u += 0x7fffu + ((u >> 16) & 1u);   // RNE; inputs finite
  return (unsigned short)(u >> 16);
}

__device__ __forceinline__ short8 pack8(float4 a, float4 b) {
  short8 r;
  r[0] = (short)f2bf(a.x); r[1] = (short)f2bf(a.y);
  r[2] = (short)f2bf(a.z); r[3] = (short)f2bf(a.w);
  r[4] = (short)f2bf(b.x); r[5] = (short)f2bf(b.y);
  r[6] = (short)f2bf(b.z); r[7] = (short)f2bf(b.w);
  return r;
}

__device__ __forceinline__ void async_lds16(const void* g, void* l) {
  __builtin_amdgcn_global_load_lds(
      (const __attribute__((address_space(1))) void*)g,
      (__attribute__((address_space(3))) void*)l, 16, 0, 0);
}

// Build VT[b][144][2048] bf16 (row d: d<128 -> emb[:,d]; 128 -> hsq; 129 -> 1; >=130 -> 0)
// and hsq[b][2048] fp32. One block per 64 nodes. (unchanged — verified)
__global__ __launch_bounds__(256) void prep_kernel(
    const float* __restrict__ emb, unsigned short* __restrict__ vt,
    float* __restrict__ hsq) {
  __shared__ float semb[64 * 132];
  __shared__ float shsq[64];
  const int t = threadIdx.x;
  const int bb = blockIdx.x >> 5;
  const int j0 = (blockIdx.x & 31) << 6;
  const float* ebase = emb + ((size_t)(bb * N_ + j0)) * D_;
#pragma unroll
  for (int it = 0; it < 8; ++it) {
    int fidx = it * 1024 + t * 4;
    int j = fidx >> 7, d = fidx & 127;
    const float4 v = *(const float4*)(ebase + (size_t)j * D_ + d);
    *(float4*)&semb[j * 132 + d] = v;
  }
  __syncthreads();
  {
    int j = t >> 2, q = t & 3;
    const float* row = &semb[j * 132 + q * 32];
    float p = 0.f;
#pragma unroll
    for (int x = 0; x < 32; ++x) p += row[x] * row[x];
    p += __shfl_down(p, 2);
    p += __shfl_down(p, 1);
    if (q == 0) { shsq[j] = p; hsq[bb * N_ + j0 + j] = p; }
  }
  __syncthreads();
  unsigned short* vbase = vt + (size_t)bb * VROWS * N_ + j0;
#pragma unroll
  for (int it = 0; it < 36; ++it) {
    int idx = it * 256 + t;
    int d = idx >> 6, j = idx & 63;
    float val;
    if (d < 128)      val = semb[j * 132 + d];
    else if (d == 128) val = shsq[j];
    else if (d == 129) val = 1.0f;
    else               val = 0.0f;
    vbase[(size_t)d * N_ + j] = f2bf(val);
  }
}

// Main GEMM: block = 32 adj rows (full contiguous 256 KB stream over K=2048).
// A fragments go global -> registers (each element used by exactly one lane);
// VT double-buffered via global_load_lds; ONE barrier per K-step; prefetch
// for step t+1 in flight across compute of step t.
__global__ __launch_bounds__(256, 2) void gemm_kernel(
    const float* __restrict__ adj, const float* __restrict__ emb,
    const float* __restrict__ hsq, const unsigned short* __restrict__ vt,
    float* __restrict__ partials) {
  __shared__ unsigned short lV[2][VROWS * BK];   // 2 x 36864 B, XOR-swizzled in 16B units
  __shared__ float red[4];

  const int t = threadIdx.x;
  const int lane = t & 63, wave = t >> 6;
  const int lhalf = lane & 15, quad = lane >> 4;
  const int mt = wave & 1;       // which 16-row half
  const int kh = wave >> 1;      // which 64-wide K-half of each BK step

  // Bijective XCD swizzle: XCD x (= bid%8) gets batch x's 64 i-tiles,
  // so each XCD's L2 caches exactly one 590 KB VT.
  const int bid = blockIdx.x;
  const int rb = (bid & 7) * (NBLK / 8) + (bid >> 3);
  const int b = rb >> 6;
  const int i0 = (rb & 63) << 5;

  const float* abase = adj + ((size_t)b << 22);
  const unsigned short* vtbase = vt + (size_t)b * VROWS * N_;
  // this lane's fragment row / K-offset within a step
  const float* arow = abase + (size_t)(i0 + mt * 16 + lhalf) * N_ + kh * 64 + quad * 8;

  f32x4 acc[9] = {};
  float4 an0, an1, an2, an3;     // in-flight A for next step (ksi0: an0/an1, ksi1: an2/an3)

  // ---- prologue: stage VT(0) into buf0, load A(0)
#pragma unroll
  for (int it = 0; it < 9; ++it) {
    int flat = it * 256 + t;
    int r = flat >> 4, up = flat & 15;
    int ul = up ^ (r & 7);
    async_lds16(vtbase + (size_t)r * N_ + ul * 8,
                (char*)&lV[0][0] + (size_t)(it * 256 + wave * 64) * 16);
  }
  an0 = *(const float4*)(arow + 0);
  an1 = *(const float4*)(arow + 4);
  an2 = *(const float4*)(arow + 32);
  an3 = *(const float4*)(arow + 36);
  __syncthreads();

  for (int ki = 0; ki < NKI; ++ki) {
    const int cur = ki & 1;
    // issue VT(ki+1) into the other buffer — in flight during compute
    if (ki + 1 < NKI) {
      const int jk = (ki + 1) * BK;
#pragma unroll
      for (int it = 0; it < 9; ++it) {
        int flat = it * 256 + t;
        int r = flat >> 4, up = flat & 15;
        int ul = up ^ (r & 7);
        async_lds16(vtbase + (size_t)r * N_ + jk + ul * 8,
                    (char*)&lV[cur ^ 1][0] + (size_t)(it * 256 + wave * 64) * 16);
      }
    }
    // convert this step's A (loaded last step; already drained by the barrier)
    short8 af0 = pack8(an0, an1);
    short8 af1 = pack8(an2, an3);
    // issue A(ki+1) — in flight during compute
    if (ki + 1 < NKI) {
      const float* ap = arow + (size_t)(ki + 1) * BK;
      an0 = *(const float4*)(ap + 0);
      an1 = *(const float4*)(ap + 4);
      an2 = *(const float4*)(ap + 32);
      an3 = *(const float4*)(ap + 36);
    }
    // compute: wave covers 16 rows (mt) x 144 cols x 64 of the 128 K (kh)
#pragma unroll
    for (int ksi = 0; ksi < 2; ++ksi) {
      const short8 a = ksi ? af1 : af0;
      const int ksf = kh * 2 + ksi;
#pragma unroll
      for (int nt = 0; nt < 9; ++nt) {
        int r = nt * 16 + lhalf;
        int up = (ksf * 4 + quad) ^ (r & 7);
        short8 bf = *(const short8*)&lV[cur][r * BK + up * 8];
        acc[nt] = __builtin_amdgcn_mfma_f32_16x16x32_bf16(a, bf, acc[nt], 0, 0, 0);
      }
    }
    __syncthreads();   // drains prefetch + publishes buf^1; one barrier per step
  }

  // ---- epilogue: part += acc[nt][rr] * U[i][d]; acc is K-partial (kh) — linear, sums fine.
  // C/D layout: col = lane&15, row = quad*4 + rr.
  float part = 0.f;
  const float* erow_base = emb + (size_t)b * N_ * D_;
#pragma unroll
  for (int rr = 0; rr < 4; ++rr) {
    int i = i0 + mt * 16 + quad * 4 + rr;
    const float* erow = erow_base + (size_t)i * D_;
#pragma unroll
    for (int nt = 0; nt < 8; ++nt) {
      int d = nt * 16 + lhalf;
      part += acc[nt][rr] * (-2.0f * erow[d]);
    }
    float u8 = (lhalf == 0) ? 1.0f : (lhalf == 1) ? hsq[b * N_ + i] : 0.0f;
    part += acc[8][rr] * u8;
  }
#pragma unroll
  for (int off = 32; off > 0; off >>= 1) part += __shfl_down(part, off);
  if (lane == 0) red[wave] = part;
  __syncthreads();
  if (t == 0) partials[rb] = red[0] + red[1] + red[2] + red[3];
}

__global__ void finish_kernel(const float* __restrict__ partials,
                              float* __restrict__ out) {
  double s = 0.0;
  int t = threadIdx.x;
  for (int i = t; i < NBLK; i += 64) s += (double)partials[i];
#pragma unroll
  for (int off = 32; off > 0; off >>= 1) s += __shfl_down(s, off);
  if (t == 0) out[0] = (float)(s / (double)((size_t)B_ * N_));
}

extern "C" void kernel_launch(void* const* d_in, const int* in_sizes, int n_in,
                              void* d_out, int out_size, void* d_ws, size_t ws_size,
                              hipStream_t stream) {
  const float* adj = (const float*)d_in[0];
  const float* emb = (const float*)d_in[1];
  // ws layout: hsq (64 KiB) | VT bf16 (4.5 MiB) | partials (2 KiB)
  float* hsq = (float*)d_ws;
  unsigned short* vt = (unsigned short*)((char*)d_ws + 65536);
  float* partials = (float*)((char*)d_ws + 65536 + (size_t)B_ * VROWS * N_ * 2);

  prep_kernel<<<B_ * (N_ / 64), 256, 0, stream>>>(emb, vt, hsq);
  gemm_kernel<<<NBLK, 256, 0, stream>>>(adj, emb, hsq, vt, partials);
  finish_kernel<<<1, 64, 0, stream>>>(partials, (float*)d_out);
}